// Round 10
// baseline (328.418 us; speedup 1.0000x reference)
//
#include <hip/hip_runtime.h>
#include <math.h>

#define NB 16        // batch
#define CH 256       // hidden
#define NH 4
#define KC 64
#define TTT 2048
#define TSS 512

typedef __attribute__((ext_vector_type(8))) short bf16x8;
typedef __attribute__((ext_vector_type(4))) float f32x4;

__device__ inline short f2bf(float x) {   // round-to-nearest-even bf16
  unsigned u = __float_as_uint(x);
  u += 0x7fffu + ((u >> 16) & 1u);
  return (short)(u >> 16);
}
__device__ inline unsigned pack2bf(float a, float b) {
  return (unsigned)(unsigned short)f2bf(a) | ((unsigned)(unsigned short)f2bf(b) << 16);
}

// fast sincos, input in revolutions (fract-reduced to [0,1), inside HW range)
__device__ inline void fast_sincos_rev(float rev, float* sn, float* cs) {
  float fr = rev - truncf(rev);
#if __has_builtin(__builtin_amdgcn_sinf)
  *sn = __builtin_amdgcn_sinf(fr);
  *cs = __builtin_amdgcn_cosf(fr);
#else
  float ang = fr * 6.28318530717958648f;
  *sn = __sinf(ang);
  *cs = __cosf(ang);
#endif
}

#define INV2PI 0.15915494309189535f
#define ROPE_C 0.28782313662425572f   // ln(10000)*2/64

// ---------------------------------------------------------------------------
// Templated tiled GEMM: Yn[b] = Wn @ X[b] + bn  (weight folds only).
// BF16OUT writes round-to-nearest-even bf16 directly (== gemm + cvt_bf16).
// ---------------------------------------------------------------------------
template <int TN, int NOUT, bool BF16OUT>
__global__ __launch_bounds__(256) void gemm_v2(
    const float* __restrict__ W0, const float* __restrict__ b0,
    const float* __restrict__ W1, const float* __restrict__ b1,
    const float* __restrict__ X, float* __restrict__ Y0, float* __restrict__ Y1,
    int K, int T) {
  constexpr int TT = 16 * TN;
  constexpr int TQ = TT / 4;
  constexpr int PB = (32 * TQ) / 256;
  const int t0 = blockIdx.x * TT;
  const int m0 = blockIdx.y * 64;
  const int b  = blockIdx.z;
  const int tid = threadIdx.x;
  const int tx = tid & 15, ty = tid >> 4;

  __shared__ float As[NOUT][32][68];
  __shared__ float Bs[32][TT + 4];

  const float* Xb = X + (size_t)b * K * T;
  float acc[NOUT][4][TN];
#pragma unroll
  for (int n = 0; n < NOUT; ++n)
#pragma unroll
    for (int i = 0; i < 4; ++i)
#pragma unroll
      for (int u = 0; u < TN; ++u) acc[n][i][u] = 0.f;

  const int am = tid >> 2, akq = tid & 3;

  for (int k0 = 0; k0 < K; k0 += 32) {
#pragma unroll
    for (int n = 0; n < NOUT; ++n) {
      const float* Wn = (n == 0) ? W0 : W1;
      float4 a0 = *(const float4*)&Wn[(size_t)(m0 + am) * K + k0 + 4 * akq];
      float4 a1 = *(const float4*)&Wn[(size_t)(m0 + am) * K + k0 + 16 + 4 * akq];
      As[n][4 * akq + 0][am] = a0.x; As[n][4 * akq + 1][am] = a0.y;
      As[n][4 * akq + 2][am] = a0.z; As[n][4 * akq + 3][am] = a0.w;
      As[n][16 + 4 * akq + 0][am] = a1.x; As[n][16 + 4 * akq + 1][am] = a1.y;
      As[n][16 + 4 * akq + 2][am] = a1.z; As[n][16 + 4 * akq + 3][am] = a1.w;
    }
#pragma unroll
    for (int p = 0; p < PB; ++p) {
      int idx = tid + p * 256;
      int t4 = idx & (TQ - 1), k = idx / TQ;
      *(float4*)&Bs[k][4 * t4] = *(const float4*)&Xb[(size_t)(k0 + k) * T + t0 + 4 * t4];
    }
    __syncthreads();
#pragma unroll
    for (int kk = 0; kk < 32; ++kk) {
      float4 av[NOUT];
#pragma unroll
      for (int n = 0; n < NOUT; ++n) av[n] = *(const float4*)&As[n][kk][4 * ty];
      float4 bv[TN / 4];
#pragma unroll
      for (int g = 0; g < TN / 4; ++g) bv[g] = *(const float4*)&Bs[kk][4 * tx + 64 * g];
#pragma unroll
      for (int n = 0; n < NOUT; ++n) {
        const float a4[4] = {av[n].x, av[n].y, av[n].z, av[n].w};
#pragma unroll
        for (int i = 0; i < 4; ++i)
#pragma unroll
          for (int g = 0; g < TN / 4; ++g) {
            acc[n][i][4 * g + 0] += a4[i] * bv[g].x;
            acc[n][i][4 * g + 1] += a4[i] * bv[g].y;
            acc[n][i][4 * g + 2] += a4[i] * bv[g].z;
            acc[n][i][4 * g + 3] += a4[i] * bv[g].w;
          }
      }
    }
    __syncthreads();
  }
#pragma unroll
  for (int n = 0; n < NOUT; ++n) {
    float* Yn = (n == 0) ? Y0 : Y1;
    const float* bn = (n == 0) ? b0 : b1;
#pragma unroll
    for (int i = 0; i < 4; ++i) {
      int row = m0 + 4 * ty + i;
      float bi = bn[row];
#pragma unroll
      for (int g = 0; g < TN / 4; ++g) {
        size_t oidx = ((size_t)b * 256 + row) * T + t0 + 4 * tx + 64 * g;
        float ox = acc[n][i][4 * g + 0] + bi, oy = acc[n][i][4 * g + 1] + bi;
        float oz = acc[n][i][4 * g + 2] + bi, ow = acc[n][i][4 * g + 3] + bi;
        if (BF16OUT) {
          uint2 w2 = make_uint2(pack2bf(ox, oy), pack2bf(oz, ow));
          *(uint2*)&((short*)Yn)[oidx] = w2;
        } else {
          *(float4*)&Yn[oidx] = make_float4(ox, oy, oz, ow);
        }
      }
    }
  }
}

// ---------------------------------------------------------------------------
// gemm_q_mfma (unchanged / passing): Q = Wq(bf16) @ x(bf16-staged) + bq,
// fused RoPE, out bf16 A-frags [bh][t][64]. r6 structure + bf16 staging.
// ---------------------------------------------------------------------------
__global__ __launch_bounds__(256, 2) void gemm_q_mfma(
    const short* __restrict__ wqbf, const float* __restrict__ bq,
    const float* __restrict__ X, short* __restrict__ qbf) {
  const int t0 = blockIdx.x * 64;
  const int b  = blockIdx.y;
  const int tid = threadIdx.x;
  const int w = tid >> 6, lane = tid & 63;
  const int quad = lane >> 4, l15 = lane & 15;

  __shared__ __align__(16) char smem[72704];
  short* Bsq = (short*)smem;          // [256k][68t] bf16, col-XOR-swizzled (34816 B)
  float* Ep  = (float*)smem;          // [256row][71t] f32 (aliased post-loop)

  // ---- stage x tile [256ch][64t] -> bf16, col-swizzled ----
  const float* xb = X + (size_t)b * CH * TTT + t0;
#pragma unroll
  for (int p = 0; p < 16; ++p) {
    int idx = tid + p * 256;
    int t4 = idx & 15, k = idx >> 4;
    int swz = ((k >> 3) & 3) * 16;
    float4 v = *(const float4*)&xb[(size_t)k * TTT + 4 * t4];
    uint2 w2 = make_uint2(pack2bf(v.x, v.y), pack2bf(v.z, v.w));
    *(uint2*)&Bsq[k * 68 + ((4 * t4) ^ swz)] = w2;
  }
  __syncthreads();

  const int mbase = w * 64;           // wave w == head w
  f32x4 acc[4][4];
#pragma unroll
  for (int mf = 0; mf < 4; ++mf)
#pragma unroll
    for (int nt = 0; nt < 4; ++nt) acc[mf][nt] = (f32x4){0.f, 0.f, 0.f, 0.f};

#pragma unroll
  for (int k0 = 0; k0 < 256; k0 += 32) {
    bf16x8 bfr[4];
#pragma unroll
    for (int nt = 0; nt < 4; ++nt) {
      int col = (nt * 16 + l15) ^ (quad * 16);
      bf16x8 f;
#pragma unroll
      for (int j = 0; j < 8; ++j)
        f[j] = Bsq[(k0 + quad * 8 + j) * 68 + col];
      bfr[nt] = f;
    }
#pragma unroll
    for (int mf = 0; mf < 4; ++mf) {
      bf16x8 af = *(const bf16x8*)&wqbf[(size_t)(mbase + mf * 16 + l15) * 256 + k0 + quad * 8];
#pragma unroll
      for (int nt = 0; nt < 4; ++nt)
        acc[mf][nt] = __builtin_amdgcn_mfma_f32_16x16x32_bf16(af, bfr[nt], acc[mf][nt], 0, 0, 0);
    }
  }
  __syncthreads();   // all Bsq reads complete; alias region becomes Ep

  // ---- acc (+bias) -> Ep [256][71] (single pass, all waves) ----
#pragma unroll
  for (int mf = 0; mf < 4; ++mf)
#pragma unroll
    for (int r = 0; r < 4; ++r) {
      int row = mbase + mf * 16 + quad * 4 + r;
      float bi = bq[row];
#pragma unroll
      for (int nt = 0; nt < 4; ++nt)
        Ep[row * 71 + nt * 16 + l15] = acc[mf][nt][r] + bi;
    }
  __syncthreads();

  // ---- rope + bf16 + transposed write (loop all 4 heads) ----
  const int tt = tid >> 2, cb = tid & 3;
  float sn[8], cs[8];
  const float tg = (float)(t0 + tt);
#pragma unroll
  for (int e = 0; e < 8; ++e) {
    float invr = __expf(-(float)(cb * 8 + e) * ROPE_C) * INV2PI;
    fast_sincos_rev(tg * invr, &sn[e], &cs[e]);
  }
#pragma unroll
  for (int hh = 0; hh < 4; ++hh) {
    float oa[8], oc[8];
#pragma unroll
    for (int e = 0; e < 8; ++e) {
      int j = cb * 8 + e;
      float a = Ep[(hh * 64 + j) * 71 + tt];
      float c = Ep[(hh * 64 + j + 32) * 71 + tt];
      oa[e] = a * cs[e] - c * sn[e];
      oc[e] = c * cs[e] + a * sn[e];
    }
    short* dst = qbf + ((size_t)(b * NH + hh) * TTT + t0 + tt) * 64 + cb * 8;
    *(uint4*)dst = make_uint4(pack2bf(oa[0], oa[1]), pack2bf(oa[2], oa[3]),
                              pack2bf(oa[4], oa[5]), pack2bf(oa[6], oa[7]));
    *(uint4*)(dst + 32) = make_uint4(pack2bf(oc[0], oc[1]), pack2bf(oc[2], oc[3]),
                                     pack2bf(oc[4], oc[5]), pack2bf(oc[6], oc[7]));
  }
}

// ---------------------------------------------------------------------------
// gemm_kv_mfma (unchanged / passing): K,V = Wkv(bf16) @ cond + b, MFMA core,
// fused rope/bf16 epilogues.
// ---------------------------------------------------------------------------
__global__ __launch_bounds__(256, 2) void gemm_kv_mfma(
    const short* __restrict__ wkvbf,  // [512 rows][512 k]: 0-255 = K, 256-511 = V
    const float* __restrict__ bk2, const float* __restrict__ bv2,
    const float* __restrict__ X, short* __restrict__ kbf, short* __restrict__ vbf) {
  const int t0 = blockIdx.x * 64;
  const int hh = blockIdx.y;
  const int b  = blockIdx.z;
  const int tid = threadIdx.x;
  const int w = tid >> 6, lane = tid & 63;
  const int quad = lane >> 4, l15 = lane & 15;

  __shared__ __align__(16) char smem[69632];
  short* Ls = (short*)smem;       // [512 k][68 s] bf16
  float* Kv = (float*)smem;       // [128 row][68 s] f32 (epilogue alias)

  const float* Xb = X + (size_t)b * 512 * TSS + t0;
#pragma unroll
  for (int p = 0; p < 32; ++p) {
    int idx = tid + p * 256;          // 0..8191
    int s4 = idx & 15, k = idx >> 4;  // k 0..511
    float4 v = *(const float4*)&Xb[(size_t)k * TSS + 4 * s4];
    uint2 w2 = make_uint2(pack2bf(v.x, v.y), pack2bf(v.z, v.w));
    *(uint2*)&Ls[k * 68 + 4 * s4] = w2;
  }
  __syncthreads();

  const int isV = w >> 1;
  const int wbase = (w & 1) * 32;
  const short* wbf = wkvbf + (size_t)(isV * 256 + hh * 64 + wbase) * 512;
  const float* bias = isV ? bv2 : bk2;

  f32x4 acc[2][4];
#pragma unroll
  for (int mf = 0; mf < 2; ++mf)
#pragma unroll
    for (int nt = 0; nt < 4; ++nt) acc[mf][nt] = (f32x4){0.f, 0.f, 0.f, 0.f};

#pragma unroll
  for (int k0 = 0; k0 < 512; k0 += 32) {
    bf16x8 bfr[4];
#pragma unroll
    for (int nt = 0; nt < 4; ++nt) {
      int s = nt * 16 + l15;
      bf16x8 f;
#pragma unroll
      for (int j = 0; j < 8; ++j)
        f[j] = Ls[(k0 + quad * 8 + j) * 68 + s];
      bfr[nt] = f;
    }
#pragma unroll
    for (int mf = 0; mf < 2; ++mf) {
      bf16x8 af = *(const bf16x8*)&wbf[(size_t)(mf * 16 + l15) * 512 + k0 + quad * 8];
#pragma unroll
      for (int nt = 0; nt < 4; ++nt)
        acc[mf][nt] = __builtin_amdgcn_mfma_f32_16x16x32_bf16(af, bfr[nt], acc[mf][nt], 0, 0, 0);
    }
  }
  __syncthreads();   // all Ls reads done; alias as Kv

#pragma unroll
  for (int mf = 0; mf < 2; ++mf)
#pragma unroll
    for (int r = 0; r < 4; ++r) {
      int lr = wbase + mf * 16 + quad * 4 + r;   // 0..63 within K or V
      int ro = isV * 64 + lr;
      float bi = bias[hh * 64 + lr];
#pragma unroll
      for (int nt = 0; nt < 4; ++nt)
        Kv[ro * 68 + nt * 16 + l15] = acc[mf][nt][r] + bi;
    }
  __syncthreads();

  const int bh = b * NH + hh;

#pragma unroll
  for (int p = 0; p < 4; ++p) {
    int idx = tid + p * 256;          // 0..1023
    int s4 = idx & 15, ch = idx >> 4; // ch 0..63
    float4 v = *(const float4*)&Kv[(64 + ch) * 68 + 4 * s4];
    uint2 w2 = make_uint2(pack2bf(v.x, v.y), pack2bf(v.z, v.w));
    *(uint2*)&vbf[((size_t)bh * KC + ch) * TSS + t0 + 4 * s4] = w2;
  }

  {
    int s = tid >> 2, g = tid & 3;
    float sg = (float)(t0 + s);
    unsigned ow[8];
#pragma unroll
    for (int hlf = 0; hlf < 8; ++hlf) {
      int ch = g * 16 + hlf * 2;
      float o2[2];
#pragma unroll
      for (int q = 0; q < 2; ++q) {
        int c = ch + q;
        int j = c & 31;
        float invr = __expf(-(float)j * ROPE_C) * INV2PI;
        float snv, csv;
        fast_sincos_rev(sg * invr, &snv, &csv);
        float a = Kv[c * 68 + s];
        float pv = Kv[(c ^ 32) * 68 + s];
        o2[q] = (c < 32) ? (a * csv - pv * snv) : (a * csv + pv * snv);
      }
      ow[hlf] = pack2bf(o2[0], o2[1]);
    }
    short* dst = kbf + ((size_t)bh * TSS + t0 + s) * 64 + g * 16;
    *(uint4*)dst = make_uint4(ow[0], ow[1], ow[2], ow[3]);
    *(uint4*)(dst + 8) = make_uint4(ow[4], ow[5], ow[6], ow[7]);
  }
}

// ---------------------------------------------------------------------------
// Bias folding (unchanged / passing)
// ---------------------------------------------------------------------------
__global__ __launch_bounds__(256) void bias_fold(
    const float* __restrict__ wk, const float* __restrict__ bk,
    const float* __restrict__ wv, const float* __restrict__ bv,
    const float* __restrict__ bcond,
    const float* __restrict__ wfilm, const float* __restrict__ bo,
    const float* __restrict__ bfilm,
    float* __restrict__ bk2, float* __restrict__ bv2, float* __restrict__ bf2) {
  int g = blockIdx.x * 256 + threadIdx.x;
  if (g < 256) {
    float s = bk[g];
    for (int k = 0; k < 256; ++k) s += wk[g * 256 + k] * bcond[k];
    bk2[g] = s;
  } else if (g < 512) {
    int m = g - 256;
    float s = bv[m];
    for (int k = 0; k < 256; ++k) s += wv[m * 256 + k] * bcond[k];
    bv2[m] = s;
  } else if (g < 1024) {
    int m = g - 512;
    float s = bfilm[m];
    for (int k = 0; k < 256; ++k) s += wfilm[m * 256 + k] * bo[k];
    bf2[m] = s;
  }
}

// ---------------------------------------------------------------------------
// fp32 -> bf16 bulk convert (wq only now)
// ---------------------------------------------------------------------------
__global__ __launch_bounds__(256) void cvt_bf16(
    const float* __restrict__ src, short* __restrict__ dst, int n) {
  int i = (blockIdx.x * 256 + threadIdx.x) * 8;
  if (i < n) {
    float4 a = *(const float4*)&src[i];
    float4 c = *(const float4*)&src[i + 4];
    uint4 w;
    w.x = pack2bf(a.x, a.y); w.y = pack2bf(a.z, a.w);
    w.z = pack2bf(c.x, c.y); w.w = pack2bf(c.z, c.w);
    *(uint4*)&dst[i] = w;
  }
}

// ---------------------------------------------------------------------------
// attn_mfma: r0 structure + pre-roped Q frags, now with a bijective
// XCD-aware 1D grid (the ONLY change vs the measured 77-µs version).
// wg runs on XCD wg%8; lin=(wg&7)*256+(wg>>3) gives each XCD a contiguous
// (b,h,tblk) range -> per-XCD K/V working set = 8 (b,h) pairs = 1 MB << L2.
// ---------------------------------------------------------------------------
__global__ __launch_bounds__(256, 3) void attn_mfma(
    const short* __restrict__ qbf, const short* __restrict__ kbf,
    const short* __restrict__ vbf, const float* __restrict__ cond_mask,
    short* __restrict__ obuf) {
  const int wg = blockIdx.x;                 // 0..2047
  const int lin = (wg & 7) * 256 + (wg >> 3);
  const int tblk = lin & 31;
  const int h = (lin >> 5) & 3;
  const int b = lin >> 7;
  const int t0 = tblk * 64;
  const int bh = b * NH + h;
  const int tid = threadIdx.x;
  const int w = tid >> 6, lane = tid & 63;
  const int quad = lane >> 4, l15 = lane & 15;

  __shared__ __align__(16) char smem[49152];
  short* Ks = (short*)smem;                 // 128x64 swizzled
  short* Vs = (short*)(smem + 16384);       // 64x128 swizzled
  short* Ps = (short*)(smem + 32768);       // 64x128 swizzled

  const short* qb = qbf + ((size_t)bh * TTT + t0) * 64;
  const int trow_l = w * 16 + l15;
  bf16x8 qf0 = *(const bf16x8*)&qb[(size_t)trow_l * 64 + quad * 8];
  bf16x8 qf1 = *(const bf16x8*)&qb[(size_t)trow_l * 64 + 32 + quad * 8];

  f32x4 acc_o[4];
#pragma unroll
  for (int n = 0; n < 4; ++n) acc_o[n] = (f32x4){0.f, 0.f, 0.f, 0.f};
  float den[4] = {0.f, 0.f, 0.f, 0.f};

  const float* cm = cond_mask + (size_t)b * TSS;
  const short* kbase = kbf + (size_t)bh * TSS * 64;
  const short* vbase = vbf + (size_t)bh * KC * TSS;

  for (int s0 = 0; s0 < TSS; s0 += 128) {
    __syncthreads();
#pragma unroll
    for (int p = 0; p < 4; ++p) {
      int idx = tid + p * 256;
      int blk = idx & 7, sr = idx >> 3;
      *(uint4*)&Ks[sr * 64 + 8 * (blk ^ (sr & 7))] =
          *(const uint4*)&kbase[(size_t)(s0 + sr) * 64 + 8 * blk];
    }
#pragma unroll
    for (int p = 0; p < 4; ++p) {
      int idx = tid + p * 256;
      int blk = idx & 15, ch = idx >> 4;
      *(uint4*)&Vs[ch * 128 + 8 * (blk ^ (ch & 7))] =
          *(const uint4*)&vbase[(size_t)ch * TSS + s0 + 8 * blk];
    }
    __syncthreads();

#pragma unroll
    for (int n0 = 0; n0 < 8; ++n0) {
      int srow = n0 * 16 + l15;
      bf16x8 kf0 = *(const bf16x8*)&Ks[srow * 64 + 8 * (quad ^ (srow & 7))];
      bf16x8 kf1 = *(const bf16x8*)&Ks[srow * 64 + 8 * ((4 + quad) ^ (srow & 7))];
      f32x4 acc = (f32x4){0.f, 0.f, 0.f, 0.f};
      acc = __builtin_amdgcn_mfma_f32_16x16x32_bf16(qf0, kf0, acc, 0, 0, 0);
      acc = __builtin_amdgcn_mfma_f32_16x16x32_bf16(qf1, kf1, acc, 0, 0, 0);
      float mk = (cm[s0 + srow] != 0.f) ? 1.f : 0.f;
      int sblk = n0 * 2 + (l15 >> 3);
      int slow = l15 & 7;
#pragma unroll
      for (int r = 0; r < 4; ++r) {
        float e = __expf(acc[r] * 0.125f) * mk;
        den[r] += e;
        int trow = w * 16 + quad * 4 + r;
        Ps[trow * 128 + 8 * (sblk ^ (trow & 7)) + slow] = f2bf(e);
      }
    }

    {
      int trow = w * 16 + l15;
#pragma unroll
      for (int kt = 0; kt < 4; ++kt) {
        bf16x8 pf = *(const bf16x8*)&Ps[trow * 128 + 8 * ((kt * 4 + quad) ^ (trow & 7))];
#pragma unroll
        for (int n0 = 0; n0 < 4; ++n0) {
          int ch = n0 * 16 + l15;
          bf16x8 vf = *(const bf16x8*)&Vs[ch * 128 + 8 * ((kt * 4 + quad) ^ (ch & 7))];
          acc_o[n0] = __builtin_amdgcn_mfma_f32_16x16x32_bf16(pf, vf, acc_o[n0], 0, 0, 0);
        }
      }
    }
  }

  float rd[4];
#pragma unroll
  for (int r = 0; r < 4; ++r) {
    float d = den[r];
#pragma unroll
    for (int off = 1; off < 16; off <<= 1) d += __shfl_xor(d, off, 16);
    rd[r] = 1.f / fmaxf(d, 1e-30f);
  }

  __syncthreads();
  short* Os = (short*)smem;
#pragma unroll
  for (int n0 = 0; n0 < 4; ++n0)
#pragma unroll
    for (int r = 0; r < 4; ++r) {
      int ch = n0 * 16 + l15;
      int trow = w * 16 + quad * 4 + r;
      Os[trow * 64 + ch] = f2bf(acc_o[n0][r] * rd[r]);
    }
  __syncthreads();

  short* ob = obuf + ((size_t)b * TTT + t0) * CH + h * KC;
#pragma unroll
  for (int p = 0; p < 2; ++p) {
    int idx = tid + p * 256;
    int t = idx >> 3, c8 = idx & 7;
    *(uint4*)&ob[(size_t)t * CH + c8 * 8] = *(const uint4*)&Os[t * 64 + c8 * 8];
  }
}

// ---------------------------------------------------------------------------
// film_mfma: t-tile 32 (was 64): grid 1024 blocks -> 4 blocks/CU (was 2),
// acc halves to [4][2] (64 VGPR), Ys 16 KB. Same swizzle/layout algebra.
// ---------------------------------------------------------------------------
__global__ __launch_bounds__(256) void film_mfma(
    const short* __restrict__ wfbf, const float* __restrict__ bf2,
    const short* __restrict__ ybf, const float* __restrict__ X,
    const float* __restrict__ xmask, float* __restrict__ out) {
  const int t0 = blockIdx.x * 32;
  const int b = blockIdx.y;
  const int tid = threadIdx.x;
  const int w = tid >> 6, lane = tid & 63;
  const int quad = lane >> 4, l15 = lane & 15;

  __shared__ __align__(16) short Ys[32 * 256];   // [t][ch] bf16, swizzled

  const short* yb = ybf + ((size_t)b * TTT + t0) * CH;
#pragma unroll
  for (int p = 0; p < 4; ++p) {
    int idx = tid + p * 256;          // 0..1023 chunks of 8 shorts
    int cb = idx & 31, tr = idx >> 5; // tr 0..31
    *(uint4*)&Ys[tr * 256 + 8 * (cb ^ (tr & 7))] =
        *(const uint4*)&yb[(size_t)tr * CH + 8 * cb];
  }
  __syncthreads();

  const int mbase = w * 64;
  f32x4 accg[4][2], accb[4][2];
#pragma unroll
  for (int mf = 0; mf < 4; ++mf)
#pragma unroll
    for (int nt = 0; nt < 2; ++nt) {
      accg[mf][nt] = (f32x4){0.f, 0.f, 0.f, 0.f};
      accb[mf][nt] = (f32x4){0.f, 0.f, 0.f, 0.f};
    }

#pragma unroll
  for (int k0 = 0; k0 < 256; k0 += 32) {
    const int cb0 = (k0 >> 3) + quad;
    bf16x8 bfr[2];
#pragma unroll
    for (int nt = 0; nt < 2; ++nt) {
      int tr = nt * 16 + l15;
      bfr[nt] = *(const bf16x8*)&Ys[tr * 256 + 8 * (cb0 ^ (tr & 7))];
    }
#pragma unroll
    for (int mf = 0; mf < 4; ++mf) {
      int rowg = mbase + mf * 16 + l15;
      bf16x8 ag = *(const bf16x8*)&wfbf[(size_t)rowg * 256 + k0 + quad * 8];
      bf16x8 ab = *(const bf16x8*)&wfbf[(size_t)(256 + rowg) * 256 + k0 + quad * 8];
#pragma unroll
      for (int nt = 0; nt < 2; ++nt) {
        accg[mf][nt] = __builtin_amdgcn_mfma_f32_16x16x32_bf16(ag, bfr[nt], accg[mf][nt], 0, 0, 0);
        accb[mf][nt] = __builtin_amdgcn_mfma_f32_16x16x32_bf16(ab, bfr[nt], accb[mf][nt], 0, 0, 0);
      }
    }
  }

  const float* xb = X + (size_t)b * CH * TTT + t0;
  const float* xm = xmask + (size_t)b * TTT + t0;
  float* ob = out + (size_t)b * CH * TTT + t0;
  float xmv[2];
#pragma unroll
  for (int nt = 0; nt < 2; ++nt) xmv[nt] = xm[nt * 16 + l15];

#pragma unroll
  for (int mf = 0; mf < 4; ++mf) {
#pragma unroll
    for (int r = 0; r < 4; ++r) {
      int row = mbase + mf * 16 + quad * 4 + r;
      float bg = bf2[row];
      float bb = bf2[256 + row];
#pragma unroll
      for (int nt = 0; nt < 2; ++nt) {
        int t = nt * 16 + l15;
        float g  = accg[mf][nt][r] + bg;
        float bt = accb[mf][nt][r] + bb;
        float xv = xb[(size_t)row * TTT + t];
        ob[(size_t)row * TTT + t] = (xv * g + bt) * xmv[nt];
      }
    }
  }
}

// ---------------------------------------------------------------------------
extern "C" void kernel_launch(void* const* d_in, const int* in_sizes, int n_in,
                              void* d_out, int out_size, void* d_ws, size_t ws_size,
                              hipStream_t stream) {
  const float* x           = (const float*)d_in[0];
  const float* x_mask      = (const float*)d_in[1];
  const float* cond_latent = (const float*)d_in[2];
  const float* cond_mask   = (const float*)d_in[3];
  const float* w_cond      = (const float*)d_in[4];
  const float* b_cond      = (const float*)d_in[5];
  const float* wq          = (const float*)d_in[6];
  const float* bq          = (const float*)d_in[7];
  const float* wk          = (const float*)d_in[8];
  const float* bk          = (const float*)d_in[9];
  const float* wv          = (const float*)d_in[10];
  const float* bv          = (const float*)d_in[11];
  const float* wo          = (const float*)d_in[12];
  const float* bo          = (const float*)d_in[13];
  const float* w_film      = (const float*)d_in[14];
  const float* b_film      = (const float*)d_in[15];
  float* out = (float*)d_out;

  float* ws = (float*)d_ws;
  float* k_buf = ws;                    // (region reused by o_bf)
  float* v_buf = k_buf + 2097152;
  float* wk2   = v_buf + 2097152;       // (unused fp32 slots kept for layout)
  float* wv2   = wk2 + 131072;
  float* wf2   = wv2 + 131072;
  float* bk2   = wf2 + 131072;          // 256
  float* bv2   = bk2 + 256;             // 256
  float* bf2   = bv2 + 256;             // 512
  float* zbuf  = bf2 + 512;             // 512 zeros
  short* k_bf  = (short*)(zbuf + 512);  // 16*4*512*64 bf16
  short* v_bf  = k_bf + 2097152;        // 16*4*64*512 bf16
  short* wf2bf = v_bf + 2097152;        // 512*256 bf16
  short* q_bf  = wf2bf + 131072;        // 16*4*2048*64 bf16
  short* wq_bf = q_bf + 8388608;        // 256*256 bf16
  short* wkv_bf = wq_bf + 65536;        // 512*512 bf16 (K rows || V rows)
  short* o_bf  = (short*)k_buf;         // 16*2048*256 bf16 (aliases k/v_buf)

  dim3 blk(256);

  hipMemsetAsync(zbuf, 0, 512 * sizeof(float), stream);

  // --- weight folding + casts (fold GEMMs emit bf16 directly) ---
  cvt_bf16<<<dim3(32), blk, 0, stream>>>(wq, wq_bf, 65536);
  gemm_v2<4, 2, true><<<dim3(8, 4, 1), blk, 0, stream>>>(
      wk, zbuf, wv, zbuf, w_cond, (float*)wkv_bf, (float*)(wkv_bf + 131072), 256, 512);
  gemm_v2<4, 1, true><<<dim3(4, 8, 1), blk, 0, stream>>>(
      w_film, zbuf, nullptr, nullptr, wo, (float*)wf2bf, nullptr, 256, 256);
  bias_fold<<<dim3(4), blk, 0, stream>>>(wk, bk, wv, bv, b_cond,
                                         w_film, bo, b_film, bk2, bv2, bf2);

  // --- main pipeline ---
  // Q projection on MFMA with fused RoPE + bf16 + transpose
  gemm_q_mfma<<<dim3(32, 16), blk, 0, stream>>>(wq_bf, bq, x, q_bf);
  // K/V projection on MFMA with fused rope/bf16 epilogues
  gemm_kv_mfma<<<dim3(8, 4, 16), blk, 0, stream>>>(
      wkv_bf, bk2, bv2, cond_latent, k_bf, v_bf);
  // MFMA attention (r0 structure, 64 t/block; XCD-swizzled 1D grid)
  attn_mfma<<<dim3(2048), blk, 0, stream>>>(q_bf, k_bf, v_bf, cond_mask, o_bf);
  // MFMA film + final output (t-tile 32, 4 blocks/CU)
  film_mfma<<<dim3(64, 16), blk, 0, stream>>>(wf2bf, bf2, o_bf, x, x_mask, out);
}

// Round 11
// 290.389 us; speedup vs baseline: 1.1310x; 1.1310x over previous
//
#include <hip/hip_runtime.h>
#include <math.h>

#define NB 16        // batch
#define CH 256       // hidden
#define NH 4
#define KC 64
#define TTT 2048
#define TSS 512

typedef __attribute__((ext_vector_type(8))) short bf16x8;
typedef __attribute__((ext_vector_type(4))) float f32x4;

__device__ inline short f2bf(float x) {   // round-to-nearest-even bf16
  unsigned u = __float_as_uint(x);
  u += 0x7fffu + ((u >> 16) & 1u);
  return (short)(u >> 16);
}
__device__ inline unsigned pack2bf(float a, float b) {
  return (unsigned)(unsigned short)f2bf(a) | ((unsigned)(unsigned short)f2bf(b) << 16);
}

// fast sincos, input in revolutions (fract-reduced to [0,1), inside HW range)
__device__ inline void fast_sincos_rev(float rev, float* sn, float* cs) {
  float fr = rev - truncf(rev);
#if __has_builtin(__builtin_amdgcn_sinf)
  *sn = __builtin_amdgcn_sinf(fr);
  *cs = __builtin_amdgcn_cosf(fr);
#else
  float ang = fr * 6.28318530717958648f;
  *sn = __sinf(ang);
  *cs = __cosf(ang);
#endif
}

#define INV2PI 0.15915494309189535f
#define ROPE_C 0.28782313662425572f   // ln(10000)*2/64

// ---------------------------------------------------------------------------
// Templated tiled GEMM: Yn[b] = Wn @ X[b] + bn  (weight folds only).
// BF16OUT writes round-to-nearest-even bf16 directly (== gemm + cvt_bf16).
// ---------------------------------------------------------------------------
template <int TN, int NOUT, bool BF16OUT>
__global__ __launch_bounds__(256) void gemm_v2(
    const float* __restrict__ W0, const float* __restrict__ b0,
    const float* __restrict__ W1, const float* __restrict__ b1,
    const float* __restrict__ X, float* __restrict__ Y0, float* __restrict__ Y1,
    int K, int T) {
  constexpr int TT = 16 * TN;
  constexpr int TQ = TT / 4;
  constexpr int PB = (32 * TQ) / 256;
  const int t0 = blockIdx.x * TT;
  const int m0 = blockIdx.y * 64;
  const int b  = blockIdx.z;
  const int tid = threadIdx.x;
  const int tx = tid & 15, ty = tid >> 4;

  __shared__ float As[NOUT][32][68];
  __shared__ float Bs[32][TT + 4];

  const float* Xb = X + (size_t)b * K * T;
  float acc[NOUT][4][TN];
#pragma unroll
  for (int n = 0; n < NOUT; ++n)
#pragma unroll
    for (int i = 0; i < 4; ++i)
#pragma unroll
      for (int u = 0; u < TN; ++u) acc[n][i][u] = 0.f;

  const int am = tid >> 2, akq = tid & 3;

  for (int k0 = 0; k0 < K; k0 += 32) {
#pragma unroll
    for (int n = 0; n < NOUT; ++n) {
      const float* Wn = (n == 0) ? W0 : W1;
      float4 a0 = *(const float4*)&Wn[(size_t)(m0 + am) * K + k0 + 4 * akq];
      float4 a1 = *(const float4*)&Wn[(size_t)(m0 + am) * K + k0 + 16 + 4 * akq];
      As[n][4 * akq + 0][am] = a0.x; As[n][4 * akq + 1][am] = a0.y;
      As[n][4 * akq + 2][am] = a0.z; As[n][4 * akq + 3][am] = a0.w;
      As[n][16 + 4 * akq + 0][am] = a1.x; As[n][16 + 4 * akq + 1][am] = a1.y;
      As[n][16 + 4 * akq + 2][am] = a1.z; As[n][16 + 4 * akq + 3][am] = a1.w;
    }
#pragma unroll
    for (int p = 0; p < PB; ++p) {
      int idx = tid + p * 256;
      int t4 = idx & (TQ - 1), k = idx / TQ;
      *(float4*)&Bs[k][4 * t4] = *(const float4*)&Xb[(size_t)(k0 + k) * T + t0 + 4 * t4];
    }
    __syncthreads();
#pragma unroll
    for (int kk = 0; kk < 32; ++kk) {
      float4 av[NOUT];
#pragma unroll
      for (int n = 0; n < NOUT; ++n) av[n] = *(const float4*)&As[n][kk][4 * ty];
      float4 bv[TN / 4];
#pragma unroll
      for (int g = 0; g < TN / 4; ++g) bv[g] = *(const float4*)&Bs[kk][4 * tx + 64 * g];
#pragma unroll
      for (int n = 0; n < NOUT; ++n) {
        const float a4[4] = {av[n].x, av[n].y, av[n].z, av[n].w};
#pragma unroll
        for (int i = 0; i < 4; ++i)
#pragma unroll
          for (int g = 0; g < TN / 4; ++g) {
            acc[n][i][4 * g + 0] += a4[i] * bv[g].x;
            acc[n][i][4 * g + 1] += a4[i] * bv[g].y;
            acc[n][i][4 * g + 2] += a4[i] * bv[g].z;
            acc[n][i][4 * g + 3] += a4[i] * bv[g].w;
          }
      }
    }
    __syncthreads();
  }
#pragma unroll
  for (int n = 0; n < NOUT; ++n) {
    float* Yn = (n == 0) ? Y0 : Y1;
    const float* bn = (n == 0) ? b0 : b1;
#pragma unroll
    for (int i = 0; i < 4; ++i) {
      int row = m0 + 4 * ty + i;
      float bi = bn[row];
#pragma unroll
      for (int g = 0; g < TN / 4; ++g) {
        size_t oidx = ((size_t)b * 256 + row) * T + t0 + 4 * tx + 64 * g;
        float ox = acc[n][i][4 * g + 0] + bi, oy = acc[n][i][4 * g + 1] + bi;
        float oz = acc[n][i][4 * g + 2] + bi, ow = acc[n][i][4 * g + 3] + bi;
        if (BF16OUT) {
          uint2 w2 = make_uint2(pack2bf(ox, oy), pack2bf(oz, ow));
          *(uint2*)&((short*)Yn)[oidx] = w2;
        } else {
          *(float4*)&Yn[oidx] = make_float4(ox, oy, oz, ow);
        }
      }
    }
  }
}

// ---------------------------------------------------------------------------
// gemm_qkv_mfma: fused Q-projection and K/V-projection. Even blocks run the
// (verified) gemm_q_mfma body, odd blocks the (verified) gemm_kv_mfma body --
// the two are data-independent (x->q_bf vs cond->k_bf/v_bf), so interleaved
// dispatch overlaps them instead of serializing two launches. Bodies are
// byte-identical to r9's kernels; only the blockIdx decode differs.
// LDS = max(72704, 69632) = 72704 -> 2 blocks/CU either path.
// ---------------------------------------------------------------------------
__global__ __launch_bounds__(256, 2) void gemm_qkv_mfma(
    const short* __restrict__ wqbf, const float* __restrict__ bq,
    const float* __restrict__ X, short* __restrict__ qbf,
    const short* __restrict__ wkvbf,
    const float* __restrict__ bk2, const float* __restrict__ bv2,
    const float* __restrict__ cond, short* __restrict__ kbf,
    short* __restrict__ vbf) {
  const int tid = threadIdx.x;
  const int w = tid >> 6, lane = tid & 63;
  const int quad = lane >> 4, l15 = lane & 15;

  __shared__ __align__(16) char smem[72704];

  if ((blockIdx.x & 1) == 0) {
    // ================= Q path (r9 gemm_q_mfma body) =================
    const int i = blockIdx.x >> 1;     // 0..511
    const int t0 = (i & 31) * 64;
    const int b  = i >> 5;

    short* Bsq = (short*)smem;          // [256k][68t] bf16, col-XOR-swizzled
    float* Ep  = (float*)smem;          // [256row][71t] f32 (aliased post-loop)

    const float* xb = X + (size_t)b * CH * TTT + t0;
#pragma unroll
    for (int p = 0; p < 16; ++p) {
      int idx = tid + p * 256;
      int t4 = idx & 15, k = idx >> 4;
      int swz = ((k >> 3) & 3) * 16;
      float4 v = *(const float4*)&xb[(size_t)k * TTT + 4 * t4];
      uint2 w2 = make_uint2(pack2bf(v.x, v.y), pack2bf(v.z, v.w));
      *(uint2*)&Bsq[k * 68 + ((4 * t4) ^ swz)] = w2;
    }
    __syncthreads();

    const int mbase = w * 64;           // wave w == head w
    f32x4 acc[4][4];
#pragma unroll
    for (int mf = 0; mf < 4; ++mf)
#pragma unroll
      for (int nt = 0; nt < 4; ++nt) acc[mf][nt] = (f32x4){0.f, 0.f, 0.f, 0.f};

#pragma unroll
    for (int k0 = 0; k0 < 256; k0 += 32) {
      bf16x8 bfr[4];
#pragma unroll
      for (int nt = 0; nt < 4; ++nt) {
        int col = (nt * 16 + l15) ^ (quad * 16);
        bf16x8 f;
#pragma unroll
        for (int j = 0; j < 8; ++j)
          f[j] = Bsq[(k0 + quad * 8 + j) * 68 + col];
        bfr[nt] = f;
      }
#pragma unroll
      for (int mf = 0; mf < 4; ++mf) {
        bf16x8 af = *(const bf16x8*)&wqbf[(size_t)(mbase + mf * 16 + l15) * 256 + k0 + quad * 8];
#pragma unroll
        for (int nt = 0; nt < 4; ++nt)
          acc[mf][nt] = __builtin_amdgcn_mfma_f32_16x16x32_bf16(af, bfr[nt], acc[mf][nt], 0, 0, 0);
      }
    }
    __syncthreads();   // all Bsq reads complete; alias region becomes Ep

#pragma unroll
    for (int mf = 0; mf < 4; ++mf)
#pragma unroll
      for (int r = 0; r < 4; ++r) {
        int row = mbase + mf * 16 + quad * 4 + r;
        float bi = bq[row];
#pragma unroll
        for (int nt = 0; nt < 4; ++nt)
          Ep[row * 71 + nt * 16 + l15] = acc[mf][nt][r] + bi;
      }
    __syncthreads();

    const int tt = tid >> 2, cb = tid & 3;
    float sn[8], cs[8];
    const float tg = (float)(t0 + tt);
#pragma unroll
    for (int e = 0; e < 8; ++e) {
      float invr = __expf(-(float)(cb * 8 + e) * ROPE_C) * INV2PI;
      fast_sincos_rev(tg * invr, &sn[e], &cs[e]);
    }
#pragma unroll
    for (int hh = 0; hh < 4; ++hh) {
      float oa[8], oc[8];
#pragma unroll
      for (int e = 0; e < 8; ++e) {
        int j = cb * 8 + e;
        float a = Ep[(hh * 64 + j) * 71 + tt];
        float c = Ep[(hh * 64 + j + 32) * 71 + tt];
        oa[e] = a * cs[e] - c * sn[e];
        oc[e] = c * cs[e] + a * sn[e];
      }
      short* dst = qbf + ((size_t)(b * NH + hh) * TTT + t0 + tt) * 64 + cb * 8;
      *(uint4*)dst = make_uint4(pack2bf(oa[0], oa[1]), pack2bf(oa[2], oa[3]),
                                pack2bf(oa[4], oa[5]), pack2bf(oa[6], oa[7]));
      *(uint4*)(dst + 32) = make_uint4(pack2bf(oc[0], oc[1]), pack2bf(oc[2], oc[3]),
                                       pack2bf(oc[4], oc[5]), pack2bf(oc[6], oc[7]));
    }
  } else {
    // ================ KV path (r9 gemm_kv_mfma body) ================
    const int i = blockIdx.x >> 1;     // 0..511
    const int t0 = (i & 7) * 64;
    const int hh = (i >> 3) & 3;
    const int b  = i >> 5;

    short* Ls = (short*)smem;       // [512 k][68 s] bf16
    float* Kv = (float*)smem;       // [128 row][68 s] f32 (epilogue alias)

    const float* Xb = cond + (size_t)b * 512 * TSS + t0;
#pragma unroll
    for (int p = 0; p < 32; ++p) {
      int idx = tid + p * 256;          // 0..8191
      int s4 = idx & 15, k = idx >> 4;  // k 0..511
      float4 v = *(const float4*)&Xb[(size_t)k * TSS + 4 * s4];
      uint2 w2 = make_uint2(pack2bf(v.x, v.y), pack2bf(v.z, v.w));
      *(uint2*)&Ls[k * 68 + 4 * s4] = w2;
    }
    __syncthreads();

    const int isV = w >> 1;
    const int wbase = (w & 1) * 32;
    const short* wbf = wkvbf + (size_t)(isV * 256 + hh * 64 + wbase) * 512;
    const float* bias = isV ? bv2 : bk2;

    f32x4 acc[2][4];
#pragma unroll
    for (int mf = 0; mf < 2; ++mf)
#pragma unroll
      for (int nt = 0; nt < 4; ++nt) acc[mf][nt] = (f32x4){0.f, 0.f, 0.f, 0.f};

#pragma unroll
    for (int k0 = 0; k0 < 512; k0 += 32) {
      bf16x8 bfr[4];
#pragma unroll
      for (int nt = 0; nt < 4; ++nt) {
        int s = nt * 16 + l15;
        bf16x8 f;
#pragma unroll
        for (int j = 0; j < 8; ++j)
          f[j] = Ls[(k0 + quad * 8 + j) * 68 + s];
        bfr[nt] = f;
      }
#pragma unroll
      for (int mf = 0; mf < 2; ++mf) {
        bf16x8 af = *(const bf16x8*)&wbf[(size_t)(mf * 16 + l15) * 512 + k0 + quad * 8];
#pragma unroll
        for (int nt = 0; nt < 4; ++nt)
          acc[mf][nt] = __builtin_amdgcn_mfma_f32_16x16x32_bf16(af, bfr[nt], acc[mf][nt], 0, 0, 0);
      }
    }
    __syncthreads();   // all Ls reads done; alias as Kv

#pragma unroll
    for (int mf = 0; mf < 2; ++mf)
#pragma unroll
      for (int r = 0; r < 4; ++r) {
        int lr = wbase + mf * 16 + quad * 4 + r;   // 0..63 within K or V
        int ro = isV * 64 + lr;
        float bi = bias[hh * 64 + lr];
#pragma unroll
        for (int nt = 0; nt < 4; ++nt)
          Kv[ro * 68 + nt * 16 + l15] = acc[mf][nt][r] + bi;
      }
    __syncthreads();

    const int bh = b * NH + hh;

#pragma unroll
    for (int p = 0; p < 4; ++p) {
      int idx = tid + p * 256;          // 0..1023
      int s4 = idx & 15, ch = idx >> 4; // ch 0..63
      float4 v = *(const float4*)&Kv[(64 + ch) * 68 + 4 * s4];
      uint2 w2 = make_uint2(pack2bf(v.x, v.y), pack2bf(v.z, v.w));
      *(uint2*)&vbf[((size_t)bh * KC + ch) * TSS + t0 + 4 * s4] = w2;
    }

    {
      int s = tid >> 2, g = tid & 3;
      float sg = (float)(t0 + s);
      unsigned ow[8];
#pragma unroll
      for (int hlf = 0; hlf < 8; ++hlf) {
        int ch = g * 16 + hlf * 2;
        float o2[2];
#pragma unroll
        for (int q = 0; q < 2; ++q) {
          int c = ch + q;
          int j = c & 31;
          float invr = __expf(-(float)j * ROPE_C) * INV2PI;
          float snv, csv;
          fast_sincos_rev(sg * invr, &snv, &csv);
          float a = Kv[c * 68 + s];
          float pv = Kv[(c ^ 32) * 68 + s];
          o2[q] = (c < 32) ? (a * csv - pv * snv) : (a * csv + pv * snv);
        }
        ow[hlf] = pack2bf(o2[0], o2[1]);
      }
      short* dst = kbf + ((size_t)bh * TSS + t0 + s) * 64 + g * 16;
      *(uint4*)dst = make_uint4(ow[0], ow[1], ow[2], ow[3]);
      *(uint4*)(dst + 8) = make_uint4(ow[4], ow[5], ow[6], ow[7]);
    }
  }
}

// ---------------------------------------------------------------------------
// Bias folding (unchanged / passing)
// ---------------------------------------------------------------------------
__global__ __launch_bounds__(256) void bias_fold(
    const float* __restrict__ wk, const float* __restrict__ bk,
    const float* __restrict__ wv, const float* __restrict__ bv,
    const float* __restrict__ bcond,
    const float* __restrict__ wfilm, const float* __restrict__ bo,
    const float* __restrict__ bfilm,
    float* __restrict__ bk2, float* __restrict__ bv2, float* __restrict__ bf2) {
  int g = blockIdx.x * 256 + threadIdx.x;
  if (g < 256) {
    float s = bk[g];
    for (int k = 0; k < 256; ++k) s += wk[g * 256 + k] * bcond[k];
    bk2[g] = s;
  } else if (g < 512) {
    int m = g - 256;
    float s = bv[m];
    for (int k = 0; k < 256; ++k) s += wv[m * 256 + k] * bcond[k];
    bv2[m] = s;
  } else if (g < 1024) {
    int m = g - 512;
    float s = bfilm[m];
    for (int k = 0; k < 256; ++k) s += wfilm[m * 256 + k] * bo[k];
    bf2[m] = s;
  }
}

// ---------------------------------------------------------------------------
// fp32 -> bf16 bulk convert (wq only now)
// ---------------------------------------------------------------------------
__global__ __launch_bounds__(256) void cvt_bf16(
    const float* __restrict__ src, short* __restrict__ dst, int n) {
  int i = (blockIdx.x * 256 + threadIdx.x) * 8;
  if (i < n) {
    float4 a = *(const float4*)&src[i];
    float4 c = *(const float4*)&src[i + 4];
    uint4 w;
    w.x = pack2bf(a.x, a.y); w.y = pack2bf(a.z, a.w);
    w.z = pack2bf(c.x, c.y); w.w = pack2bf(c.z, c.w);
    *(uint4*)&dst[i] = w;
  }
}

// ---------------------------------------------------------------------------
// attn_mfma (r9 exact): r0 structure + direct pre-roped Q frags, grid
// (32,4,16). FETCH-reducing XCD swizzle tested r9: traffic -68% but dur
// unchanged -> attn is structure-stall-bound, not miss-latency-bound.
// ---------------------------------------------------------------------------
__global__ __launch_bounds__(256, 3) void attn_mfma(
    const short* __restrict__ qbf, const short* __restrict__ kbf,
    const short* __restrict__ vbf, const float* __restrict__ cond_mask,
    short* __restrict__ obuf) {
  const int t0 = blockIdx.x * 64;
  const int h = blockIdx.y, b = blockIdx.z;
  const int bh = b * NH + h;
  const int tid = threadIdx.x;
  const int w = tid >> 6, lane = tid & 63;
  const int quad = lane >> 4, l15 = lane & 15;

  __shared__ __align__(16) char smem[49152];
  short* Ks = (short*)smem;                 // 128x64 swizzled
  short* Vs = (short*)(smem + 16384);       // 64x128 swizzled
  short* Ps = (short*)(smem + 32768);       // 64x128 swizzled

  const short* qb = qbf + ((size_t)bh * TTT + t0) * 64;
  const int trow_l = w * 16 + l15;
  bf16x8 qf0 = *(const bf16x8*)&qb[(size_t)trow_l * 64 + quad * 8];
  bf16x8 qf1 = *(const bf16x8*)&qb[(size_t)trow_l * 64 + 32 + quad * 8];

  f32x4 acc_o[4];
#pragma unroll
  for (int n = 0; n < 4; ++n) acc_o[n] = (f32x4){0.f, 0.f, 0.f, 0.f};
  float den[4] = {0.f, 0.f, 0.f, 0.f};

  const float* cm = cond_mask + (size_t)b * TSS;
  const short* kbase = kbf + (size_t)bh * TSS * 64;
  const short* vbase = vbf + (size_t)bh * KC * TSS;

  for (int s0 = 0; s0 < TSS; s0 += 128) {
    __syncthreads();
#pragma unroll
    for (int p = 0; p < 4; ++p) {
      int idx = tid + p * 256;
      int blk = idx & 7, sr = idx >> 3;
      *(uint4*)&Ks[sr * 64 + 8 * (blk ^ (sr & 7))] =
          *(const uint4*)&kbase[(size_t)(s0 + sr) * 64 + 8 * blk];
    }
#pragma unroll
    for (int p = 0; p < 4; ++p) {
      int idx = tid + p * 256;
      int blk = idx & 15, ch = idx >> 4;
      *(uint4*)&Vs[ch * 128 + 8 * (blk ^ (ch & 7))] =
          *(const uint4*)&vbase[(size_t)ch * TSS + s0 + 8 * blk];
    }
    __syncthreads();

#pragma unroll
    for (int n0 = 0; n0 < 8; ++n0) {
      int srow = n0 * 16 + l15;
      bf16x8 kf0 = *(const bf16x8*)&Ks[srow * 64 + 8 * (quad ^ (srow & 7))];
      bf16x8 kf1 = *(const bf16x8*)&Ks[srow * 64 + 8 * ((4 + quad) ^ (srow & 7))];
      f32x4 acc = (f32x4){0.f, 0.f, 0.f, 0.f};
      acc = __builtin_amdgcn_mfma_f32_16x16x32_bf16(qf0, kf0, acc, 0, 0, 0);
      acc = __builtin_amdgcn_mfma_f32_16x16x32_bf16(qf1, kf1, acc, 0, 0, 0);
      float mk = (cm[s0 + srow] != 0.f) ? 1.f : 0.f;
      int sblk = n0 * 2 + (l15 >> 3);
      int slow = l15 & 7;
#pragma unroll
      for (int r = 0; r < 4; ++r) {
        float e = __expf(acc[r] * 0.125f) * mk;
        den[r] += e;
        int trow = w * 16 + quad * 4 + r;
        Ps[trow * 128 + 8 * (sblk ^ (trow & 7)) + slow] = f2bf(e);
      }
    }

    {
      int trow = w * 16 + l15;
#pragma unroll
      for (int kt = 0; kt < 4; ++kt) {
        bf16x8 pf = *(const bf16x8*)&Ps[trow * 128 + 8 * ((kt * 4 + quad) ^ (trow & 7))];
#pragma unroll
        for (int n0 = 0; n0 < 4; ++n0) {
          int ch = n0 * 16 + l15;
          bf16x8 vf = *(const bf16x8*)&Vs[ch * 128 + 8 * ((kt * 4 + quad) ^ (ch & 7))];
          acc_o[n0] = __builtin_amdgcn_mfma_f32_16x16x32_bf16(pf, vf, acc_o[n0], 0, 0, 0);
        }
      }
    }
  }

  float rd[4];
#pragma unroll
  for (int r = 0; r < 4; ++r) {
    float d = den[r];
#pragma unroll
    for (int off = 1; off < 16; off <<= 1) d += __shfl_xor(d, off, 16);
    rd[r] = 1.f / fmaxf(d, 1e-30f);
  }

  __syncthreads();
  short* Os = (short*)smem;
#pragma unroll
  for (int n0 = 0; n0 < 4; ++n0)
#pragma unroll
    for (int r = 0; r < 4; ++r) {
      int ch = n0 * 16 + l15;
      int trow = w * 16 + quad * 4 + r;
      Os[trow * 64 + ch] = f2bf(acc_o[n0][r] * rd[r]);
    }
  __syncthreads();

  short* ob = obuf + ((size_t)b * TTT + t0) * CH + h * KC;
#pragma unroll
  for (int p = 0; p < 2; ++p) {
    int idx = tid + p * 256;
    int t = idx >> 3, c8 = idx & 7;
    *(uint4*)&ob[(size_t)t * CH + c8 * 8] = *(const uint4*)&Os[t * 64 + c8 * 8];
  }
}

// ---------------------------------------------------------------------------
// film_mfma (r9 exact, t-tile 64): the t32 variant regressed ~35 µs (r10).
// ---------------------------------------------------------------------------
__global__ __launch_bounds__(256) void film_mfma(
    const short* __restrict__ wfbf, const float* __restrict__ bf2,
    const short* __restrict__ ybf, const float* __restrict__ X,
    const float* __restrict__ xmask, float* __restrict__ out) {
  const int t0 = blockIdx.x * 64;
  const int b = blockIdx.y;
  const int tid = threadIdx.x;
  const int w = tid >> 6, lane = tid & 63;
  const int quad = lane >> 4, l15 = lane & 15;

  __shared__ __align__(16) short Ys[64 * 256];

  const short* yb = ybf + ((size_t)b * TTT + t0) * CH;
#pragma unroll
  for (int p = 0; p < 8; ++p) {
    int idx = tid + p * 256;
    int cb = idx & 31, tr = idx >> 5;
    *(uint4*)&Ys[tr * 256 + 8 * (cb ^ (tr & 7))] =
        *(const uint4*)&yb[(size_t)tr * CH + 8 * cb];
  }
  __syncthreads();

  const int mbase = w * 64;
  f32x4 accg[4][4], accb[4][4];
#pragma unroll
  for (int mf = 0; mf < 4; ++mf)
#pragma unroll
    for (int nt = 0; nt < 4; ++nt) {
      accg[mf][nt] = (f32x4){0.f, 0.f, 0.f, 0.f};
      accb[mf][nt] = (f32x4){0.f, 0.f, 0.f, 0.f};
    }

#pragma unroll
  for (int k0 = 0; k0 < 256; k0 += 32) {
    const int cb0 = (k0 >> 3) + quad;
    bf16x8 bfr[4];
#pragma unroll
    for (int nt = 0; nt < 4; ++nt) {
      int tr = nt * 16 + l15;
      bfr[nt] = *(const bf16x8*)&Ys[tr * 256 + 8 * (cb0 ^ (tr & 7))];
    }
#pragma unroll
    for (int mf = 0; mf < 4; ++mf) {
      int rowg = mbase + mf * 16 + l15;
      bf16x8 ag = *(const bf16x8*)&wfbf[(size_t)rowg * 256 + k0 + quad * 8];
      bf16x8 ab = *(const bf16x8*)&wfbf[(size_t)(256 + rowg) * 256 + k0 + quad * 8];
#pragma unroll
      for (int nt = 0; nt < 4; ++nt) {
        accg[mf][nt] = __builtin_amdgcn_mfma_f32_16x16x32_bf16(ag, bfr[nt], accg[mf][nt], 0, 0, 0);
        accb[mf][nt] = __builtin_amdgcn_mfma_f32_16x16x32_bf16(ab, bfr[nt], accb[mf][nt], 0, 0, 0);
      }
    }
  }

  const float* xb = X + (size_t)b * CH * TTT + t0;
  const float* xm = xmask + (size_t)b * TTT + t0;
  float* ob = out + (size_t)b * CH * TTT + t0;
  float xmv[4];
#pragma unroll
  for (int nt = 0; nt < 4; ++nt) xmv[nt] = xm[nt * 16 + l15];

#pragma unroll
  for (int mf = 0; mf < 4; ++mf) {
#pragma unroll
    for (int r = 0; r < 4; ++r) {
      int row = mbase + mf * 16 + quad * 4 + r;
      float bg = bf2[row];
      float bb = bf2[256 + row];
#pragma unroll
      for (int nt = 0; nt < 4; ++nt) {
        int t = nt * 16 + l15;
        float g  = accg[mf][nt][r] + bg;
        float bt = accb[mf][nt][r] + bb;
        float xv = xb[(size_t)row * TTT + t];
        ob[(size_t)row * TTT + t] = (xv * g + bt) * xmv[nt];
      }
    }
  }
}

// ---------------------------------------------------------------------------
extern "C" void kernel_launch(void* const* d_in, const int* in_sizes, int n_in,
                              void* d_out, int out_size, void* d_ws, size_t ws_size,
                              hipStream_t stream) {
  const float* x           = (const float*)d_in[0];
  const float* x_mask      = (const float*)d_in[1];
  const float* cond_latent = (const float*)d_in[2];
  const float* cond_mask   = (const float*)d_in[3];
  const float* w_cond      = (const float*)d_in[4];
  const float* b_cond      = (const float*)d_in[5];
  const float* wq          = (const float*)d_in[6];
  const float* bq          = (const float*)d_in[7];
  const float* wk          = (const float*)d_in[8];
  const float* bk          = (const float*)d_in[9];
  const float* wv          = (const float*)d_in[10];
  const float* bv          = (const float*)d_in[11];
  const float* wo          = (const float*)d_in[12];
  const float* bo          = (const float*)d_in[13];
  const float* w_film      = (const float*)d_in[14];
  const float* b_film      = (const float*)d_in[15];
  float* out = (float*)d_out;

  float* ws = (float*)d_ws;
  float* k_buf = ws;                    // (region reused by o_bf)
  float* v_buf = k_buf + 2097152;
  float* wk2   = v_buf + 2097152;       // (unused fp32 slots kept for layout)
  float* wv2   = wk2 + 131072;
  float* wf2   = wv2 + 131072;
  float* bk2   = wf2 + 131072;          // 256
  float* bv2   = bk2 + 256;             // 256
  float* bf2   = bv2 + 256;             // 512
  float* zbuf  = bf2 + 512;             // 512 zeros
  short* k_bf  = (short*)(zbuf + 512);  // 16*4*512*64 bf16
  short* v_bf  = k_bf + 2097152;        // 16*4*64*512 bf16
  short* wf2bf = v_bf + 2097152;        // 512*256 bf16
  short* q_bf  = wf2bf + 131072;        // 16*4*2048*64 bf16
  short* wq_bf = q_bf + 8388608;        // 256*256 bf16
  short* wkv_bf = wq_bf + 65536;        // 512*512 bf16 (K rows || V rows)
  short* o_bf  = (short*)k_buf;         // 16*2048*256 bf16 (aliases k/v_buf)

  dim3 blk(256);

  hipMemsetAsync(zbuf, 0, 512 * sizeof(float), stream);

  // --- weight folding + casts (fold GEMMs emit bf16 directly) ---
  cvt_bf16<<<dim3(32), blk, 0, stream>>>(wq, wq_bf, 65536);
  gemm_v2<4, 2, true><<<dim3(8, 4, 1), blk, 0, stream>>>(
      wk, zbuf, wv, zbuf, w_cond, (float*)wkv_bf, (float*)(wkv_bf + 131072), 256, 512);
  gemm_v2<4, 1, true><<<dim3(4, 8, 1), blk, 0, stream>>>(
      w_film, zbuf, nullptr, nullptr, wo, (float*)wf2bf, nullptr, 256, 256);
  bias_fold<<<dim3(4), blk, 0, stream>>>(wk, bk, wv, bv, b_cond,
                                         w_film, bo, b_film, bk2, bv2, bf2);

  // --- main pipeline ---
  // Fused Q + K/V projections (independent; interleaved blocks overlap them)
  gemm_qkv_mfma<<<dim3(1024), blk, 0, stream>>>(
      wq_bf, bq, x, q_bf, wkv_bf, bk2, bv2, cond_latent, k_bf, v_bf);
  // MFMA attention (r0 structure, 64 t/block)
  attn_mfma<<<dim3(32, 4, 16), blk, 0, stream>>>(q_bf, k_bf, v_bf, cond_mask, o_bf);
  // MFMA film + final output (t-tile 64)
  film_mfma<<<dim3(32, 16), blk, 0, stream>>>(wf2bf, bf2, o_bf, x, x_mask, out);
}

// Round 12
// 259.491 us; speedup vs baseline: 1.2656x; 1.1191x over previous
//
#include <hip/hip_runtime.h>
#include <math.h>

#define NB 16        // batch
#define CH 256       // hidden
#define NH 4
#define KC 64
#define TTT 2048
#define TSS 512

typedef __attribute__((ext_vector_type(8))) short bf16x8;
typedef __attribute__((ext_vector_type(4))) float f32x4;

__device__ inline short f2bf(float x) {   // round-to-nearest-even bf16
  unsigned u = __float_as_uint(x);
  u += 0x7fffu + ((u >> 16) & 1u);
  return (short)(u >> 16);
}
__device__ inline unsigned pack2bf(float a, float b) {
  return (unsigned)(unsigned short)f2bf(a) | ((unsigned)(unsigned short)f2bf(b) << 16);
}

// fast sincos, input in revolutions (fract-reduced to [0,1), inside HW range)
__device__ inline void fast_sincos_rev(float rev, float* sn, float* cs) {
  float fr = rev - truncf(rev);
#if __has_builtin(__builtin_amdgcn_sinf)
  *sn = __builtin_amdgcn_sinf(fr);
  *cs = __builtin_amdgcn_cosf(fr);
#else
  float ang = fr * 6.28318530717958648f;
  *sn = __sinf(ang);
  *cs = __cosf(ang);
#endif
}

#define INV2PI 0.15915494309189535f
#define ROPE_C 0.28782313662425572f   // ln(10000)*2/64

// ---------------------------------------------------------------------------
// fold_gemm: device body of the (verified) gemm_v2<4,NOUT,true> weight-fold,
// specialized to b=0, zero bias, bf16 output. Byte-identical arithmetic.
// ---------------------------------------------------------------------------
template <int NOUT>
__device__ __forceinline__ void fold_gemm(
    const float* __restrict__ W0, const float* __restrict__ W1,
    const float* __restrict__ X, short* __restrict__ Y0, short* __restrict__ Y1,
    int K, int T, int bx, int by, char* smraw) {
  const int t0 = bx * 64;
  const int m0 = by * 64;
  const int tid = threadIdx.x;
  const int tx = tid & 15, ty = tid >> 4;

  float* As = (float*)smraw;                         // [NOUT][32][68]
  float* Bs = (float*)(smraw + NOUT * 32 * 68 * 4);  // [32][68]

  float acc[NOUT][4][4];
#pragma unroll
  for (int n = 0; n < NOUT; ++n)
#pragma unroll
    for (int i = 0; i < 4; ++i)
#pragma unroll
      for (int u = 0; u < 4; ++u) acc[n][i][u] = 0.f;

  const int am = tid >> 2, akq = tid & 3;

  for (int k0 = 0; k0 < K; k0 += 32) {
#pragma unroll
    for (int n = 0; n < NOUT; ++n) {
      const float* Wn = (n == 0) ? W0 : W1;
      float* An = As + n * 32 * 68;
      float4 a0 = *(const float4*)&Wn[(size_t)(m0 + am) * K + k0 + 4 * akq];
      float4 a1 = *(const float4*)&Wn[(size_t)(m0 + am) * K + k0 + 16 + 4 * akq];
      An[(4 * akq + 0) * 68 + am] = a0.x; An[(4 * akq + 1) * 68 + am] = a0.y;
      An[(4 * akq + 2) * 68 + am] = a0.z; An[(4 * akq + 3) * 68 + am] = a0.w;
      An[(16 + 4 * akq + 0) * 68 + am] = a1.x; An[(16 + 4 * akq + 1) * 68 + am] = a1.y;
      An[(16 + 4 * akq + 2) * 68 + am] = a1.z; An[(16 + 4 * akq + 3) * 68 + am] = a1.w;
    }
#pragma unroll
    for (int p = 0; p < 2; ++p) {
      int idx = tid + p * 256;
      int t4 = idx & 15, k = idx >> 4;
      *(float4*)&Bs[k * 68 + 4 * t4] = *(const float4*)&X[(size_t)(k0 + k) * T + t0 + 4 * t4];
    }
    __syncthreads();
#pragma unroll
    for (int kk = 0; kk < 32; ++kk) {
      float4 bv = *(const float4*)&Bs[kk * 68 + 4 * tx];
#pragma unroll
      for (int n = 0; n < NOUT; ++n) {
        float4 av = *(const float4*)&As[n * 32 * 68 + kk * 68 + 4 * ty];
        const float a4[4] = {av.x, av.y, av.z, av.w};
#pragma unroll
        for (int i = 0; i < 4; ++i) {
          acc[n][i][0] += a4[i] * bv.x; acc[n][i][1] += a4[i] * bv.y;
          acc[n][i][2] += a4[i] * bv.z; acc[n][i][3] += a4[i] * bv.w;
        }
      }
    }
    __syncthreads();
  }
#pragma unroll
  for (int n = 0; n < NOUT; ++n) {
    short* Yn = (n == 0) ? Y0 : Y1;
#pragma unroll
    for (int i = 0; i < 4; ++i) {
      int row = m0 + 4 * ty + i;
      uint2 w2 = make_uint2(pack2bf(acc[n][i][0], acc[n][i][1]),
                            pack2bf(acc[n][i][2], acc[n][i][3]));
      *(uint2*)&Yn[(size_t)row * T + t0 + 4 * tx] = w2;
    }
  }
}

// ---------------------------------------------------------------------------
// prep: ALL weight folding in one launch (was memset + 4 kernels).
// blocks 0-31:  kv fold   (wk,wv @ w_cond -> wkv_bf, bf16)
// blocks 32-63: film fold (w_film @ wo -> wf2bf, bf16)
// blocks 64-95: wq fp32->bf16 cvt
// blocks 96-99: bias folds (bk2, bv2, bf2)
// Sub-kernels are mutually independent; concurrent instead of serialized.
// ---------------------------------------------------------------------------
__global__ __launch_bounds__(256) void prep(
    const float* __restrict__ wk, const float* __restrict__ wv,
    const float* __restrict__ w_cond, short* __restrict__ wkv_bf,
    const float* __restrict__ w_film, const float* __restrict__ wo,
    short* __restrict__ wf2bf,
    const float* __restrict__ wq, short* __restrict__ wq_bf,
    const float* __restrict__ bk, const float* __restrict__ bv,
    const float* __restrict__ b_cond, const float* __restrict__ b_film,
    const float* __restrict__ bo,
    float* __restrict__ bk2, float* __restrict__ bv2, float* __restrict__ bf2) {
  __shared__ __align__(16) char psm[26112];
  const int g = blockIdx.x;
  const int tid = threadIdx.x;

  if (g < 32) {
    // kv fold: grid was (8,4): bx = g&7, by = g>>3; K=256, T=512
    fold_gemm<2>(wk, wv, w_cond, wkv_bf, wkv_bf + 131072, 256, 512, g & 7, g >> 3, psm);
  } else if (g < 64) {
    // film fold: grid was (4,8): bx = (g-32)&3, by = (g-32)>>2; K=256, T=256
    int i = g - 32;
    fold_gemm<1>(w_film, nullptr, wo, wf2bf, nullptr, 256, 256, i & 3, i >> 2, psm);
  } else if (g < 96) {
    // wq cvt: 32 blocks x 256 threads x 8 elems = 65536
    int i = ((g - 64) * 256 + tid) * 8;
    float4 a = *(const float4*)&wq[i];
    float4 c = *(const float4*)&wq[i + 4];
    uint4 w;
    w.x = pack2bf(a.x, a.y); w.y = pack2bf(a.z, a.w);
    w.z = pack2bf(c.x, c.y); w.w = pack2bf(c.z, c.w);
    *(uint4*)&wq_bf[i] = w;
  } else {
    // bias folds: 4 blocks -> g2 0..1023
    int g2 = (g - 96) * 256 + tid;
    if (g2 < 256) {
      float s = bk[g2];
      for (int k = 0; k < 256; ++k) s += wk[g2 * 256 + k] * b_cond[k];
      bk2[g2] = s;
    } else if (g2 < 512) {
      int m = g2 - 256;
      float s = bv[m];
      for (int k = 0; k < 256; ++k) s += wv[m * 256 + k] * b_cond[k];
      bv2[m] = s;
    } else if (g2 < 1024) {
      int m = g2 - 512;
      float s = b_film[m];
      for (int k = 0; k < 256; ++k) s += w_film[m * 256 + k] * bo[k];
      bf2[m] = s;
    }
  }
}

// ---------------------------------------------------------------------------
// gemm_qkv_mfma (r11 exact): fused Q-projection and K/V-projection.
// ---------------------------------------------------------------------------
__global__ __launch_bounds__(256, 2) void gemm_qkv_mfma(
    const short* __restrict__ wqbf, const float* __restrict__ bq,
    const float* __restrict__ X, short* __restrict__ qbf,
    const short* __restrict__ wkvbf,
    const float* __restrict__ bk2, const float* __restrict__ bv2,
    const float* __restrict__ cond, short* __restrict__ kbf,
    short* __restrict__ vbf) {
  const int tid = threadIdx.x;
  const int w = tid >> 6, lane = tid & 63;
  const int quad = lane >> 4, l15 = lane & 15;

  __shared__ __align__(16) char smem[72704];

  if ((blockIdx.x & 1) == 0) {
    // ================= Q path =================
    const int i = blockIdx.x >> 1;     // 0..511
    const int t0 = (i & 31) * 64;
    const int b  = i >> 5;

    short* Bsq = (short*)smem;          // [256k][68t] bf16, col-XOR-swizzled
    float* Ep  = (float*)smem;          // [256row][71t] f32 (aliased post-loop)

    const float* xb = X + (size_t)b * CH * TTT + t0;
#pragma unroll
    for (int p = 0; p < 16; ++p) {
      int idx = tid + p * 256;
      int t4 = idx & 15, k = idx >> 4;
      int swz = ((k >> 3) & 3) * 16;
      float4 v = *(const float4*)&xb[(size_t)k * TTT + 4 * t4];
      uint2 w2 = make_uint2(pack2bf(v.x, v.y), pack2bf(v.z, v.w));
      *(uint2*)&Bsq[k * 68 + ((4 * t4) ^ swz)] = w2;
    }
    __syncthreads();

    const int mbase = w * 64;           // wave w == head w
    f32x4 acc[4][4];
#pragma unroll
    for (int mf = 0; mf < 4; ++mf)
#pragma unroll
      for (int nt = 0; nt < 4; ++nt) acc[mf][nt] = (f32x4){0.f, 0.f, 0.f, 0.f};

#pragma unroll
    for (int k0 = 0; k0 < 256; k0 += 32) {
      bf16x8 bfr[4];
#pragma unroll
      for (int nt = 0; nt < 4; ++nt) {
        int col = (nt * 16 + l15) ^ (quad * 16);
        bf16x8 f;
#pragma unroll
        for (int j = 0; j < 8; ++j)
          f[j] = Bsq[(k0 + quad * 8 + j) * 68 + col];
        bfr[nt] = f;
      }
#pragma unroll
      for (int mf = 0; mf < 4; ++mf) {
        bf16x8 af = *(const bf16x8*)&wqbf[(size_t)(mbase + mf * 16 + l15) * 256 + k0 + quad * 8];
#pragma unroll
        for (int nt = 0; nt < 4; ++nt)
          acc[mf][nt] = __builtin_amdgcn_mfma_f32_16x16x32_bf16(af, bfr[nt], acc[mf][nt], 0, 0, 0);
      }
    }
    __syncthreads();   // all Bsq reads complete; alias region becomes Ep

#pragma unroll
    for (int mf = 0; mf < 4; ++mf)
#pragma unroll
      for (int r = 0; r < 4; ++r) {
        int row = mbase + mf * 16 + quad * 4 + r;
        float bi = bq[row];
#pragma unroll
        for (int nt = 0; nt < 4; ++nt)
          Ep[row * 71 + nt * 16 + l15] = acc[mf][nt][r] + bi;
      }
    __syncthreads();

    const int tt = tid >> 2, cb = tid & 3;
    float sn[8], cs[8];
    const float tg = (float)(t0 + tt);
#pragma unroll
    for (int e = 0; e < 8; ++e) {
      float invr = __expf(-(float)(cb * 8 + e) * ROPE_C) * INV2PI;
      fast_sincos_rev(tg * invr, &sn[e], &cs[e]);
    }
#pragma unroll
    for (int hh = 0; hh < 4; ++hh) {
      float oa[8], oc[8];
#pragma unroll
      for (int e = 0; e < 8; ++e) {
        int j = cb * 8 + e;
        float a = Ep[(hh * 64 + j) * 71 + tt];
        float c = Ep[(hh * 64 + j + 32) * 71 + tt];
        oa[e] = a * cs[e] - c * sn[e];
        oc[e] = c * cs[e] + a * sn[e];
      }
      short* dst = qbf + ((size_t)(b * NH + hh) * TTT + t0 + tt) * 64 + cb * 8;
      *(uint4*)dst = make_uint4(pack2bf(oa[0], oa[1]), pack2bf(oa[2], oa[3]),
                                pack2bf(oa[4], oa[5]), pack2bf(oa[6], oa[7]));
      *(uint4*)(dst + 32) = make_uint4(pack2bf(oc[0], oc[1]), pack2bf(oc[2], oc[3]),
                                       pack2bf(oc[4], oc[5]), pack2bf(oc[6], oc[7]));
    }
  } else {
    // ================ KV path ================
    const int i = blockIdx.x >> 1;     // 0..511
    const int t0 = (i & 7) * 64;
    const int hh = (i >> 3) & 3;
    const int b  = i >> 5;

    short* Ls = (short*)smem;       // [512 k][68 s] bf16
    float* Kv = (float*)smem;       // [128 row][68 s] f32 (epilogue alias)

    const float* Xb = cond + (size_t)b * 512 * TSS + t0;
#pragma unroll
    for (int p = 0; p < 32; ++p) {
      int idx = tid + p * 256;          // 0..8191
      int s4 = idx & 15, k = idx >> 4;  // k 0..511
      float4 v = *(const float4*)&Xb[(size_t)k * TSS + 4 * s4];
      uint2 w2 = make_uint2(pack2bf(v.x, v.y), pack2bf(v.z, v.w));
      *(uint2*)&Ls[k * 68 + 4 * s4] = w2;
    }
    __syncthreads();

    const int isV = w >> 1;
    const int wbase = (w & 1) * 32;
    const short* wbf = wkvbf + (size_t)(isV * 256 + hh * 64 + wbase) * 512;
    const float* bias = isV ? bv2 : bk2;

    f32x4 acc[2][4];
#pragma unroll
    for (int mf = 0; mf < 2; ++mf)
#pragma unroll
      for (int nt = 0; nt < 4; ++nt) acc[mf][nt] = (f32x4){0.f, 0.f, 0.f, 0.f};

#pragma unroll
    for (int k0 = 0; k0 < 512; k0 += 32) {
      bf16x8 bfr[4];
#pragma unroll
      for (int nt = 0; nt < 4; ++nt) {
        int s = nt * 16 + l15;
        bf16x8 f;
#pragma unroll
        for (int j = 0; j < 8; ++j)
          f[j] = Ls[(k0 + quad * 8 + j) * 68 + s];
        bfr[nt] = f;
      }
#pragma unroll
      for (int mf = 0; mf < 2; ++mf) {
        bf16x8 af = *(const bf16x8*)&wbf[(size_t)(mf * 16 + l15) * 512 + k0 + quad * 8];
#pragma unroll
        for (int nt = 0; nt < 4; ++nt)
          acc[mf][nt] = __builtin_amdgcn_mfma_f32_16x16x32_bf16(af, bfr[nt], acc[mf][nt], 0, 0, 0);
      }
    }
    __syncthreads();   // all Ls reads done; alias as Kv

#pragma unroll
    for (int mf = 0; mf < 2; ++mf)
#pragma unroll
      for (int r = 0; r < 4; ++r) {
        int lr = wbase + mf * 16 + quad * 4 + r;   // 0..63 within K or V
        int ro = isV * 64 + lr;
        float bi = bias[hh * 64 + lr];
#pragma unroll
        for (int nt = 0; nt < 4; ++nt)
          Kv[ro * 68 + nt * 16 + l15] = acc[mf][nt][r] + bi;
      }
    __syncthreads();

    const int bh = b * NH + hh;

#pragma unroll
    for (int p = 0; p < 4; ++p) {
      int idx = tid + p * 256;          // 0..1023
      int s4 = idx & 15, ch = idx >> 4; // ch 0..63
      float4 v = *(const float4*)&Kv[(64 + ch) * 68 + 4 * s4];
      uint2 w2 = make_uint2(pack2bf(v.x, v.y), pack2bf(v.z, v.w));
      *(uint2*)&vbf[((size_t)bh * KC + ch) * TSS + t0 + 4 * s4] = w2;
    }

    {
      int s = tid >> 2, g = tid & 3;
      float sg = (float)(t0 + s);
      unsigned ow[8];
#pragma unroll
      for (int hlf = 0; hlf < 8; ++hlf) {
        int ch = g * 16 + hlf * 2;
        float o2[2];
#pragma unroll
        for (int q = 0; q < 2; ++q) {
          int c = ch + q;
          int j = c & 31;
          float invr = __expf(-(float)j * ROPE_C) * INV2PI;
          float snv, csv;
          fast_sincos_rev(sg * invr, &snv, &csv);
          float a = Kv[c * 68 + s];
          float pv = Kv[(c ^ 32) * 68 + s];
          o2[q] = (c < 32) ? (a * csv - pv * snv) : (a * csv + pv * snv);
        }
        ow[hlf] = pack2bf(o2[0], o2[1]);
      }
      short* dst = kbf + ((size_t)bh * TSS + t0 + s) * 64 + g * 16;
      *(uint4*)dst = make_uint4(ow[0], ow[1], ow[2], ow[3]);
      *(uint4*)(dst + 8) = make_uint4(ow[4], ow[5], ow[6], ow[7]);
    }
  }
}

// ---------------------------------------------------------------------------
// attn_mfma (r9 exact): r0 structure + direct pre-roped Q frags, grid
// (32,4,16). XCD swizzle tested r9: FETCH -68% but dur unchanged -> attn is
// structure-stall-bound, not miss-latency-bound. Do not touch.
// ---------------------------------------------------------------------------
__global__ __launch_bounds__(256, 3) void attn_mfma(
    const short* __restrict__ qbf, const short* __restrict__ kbf,
    const short* __restrict__ vbf, const float* __restrict__ cond_mask,
    short* __restrict__ obuf) {
  const int t0 = blockIdx.x * 64;
  const int h = blockIdx.y, b = blockIdx.z;
  const int bh = b * NH + h;
  const int tid = threadIdx.x;
  const int w = tid >> 6, lane = tid & 63;
  const int quad = lane >> 4, l15 = lane & 15;

  __shared__ __align__(16) char smem[49152];
  short* Ks = (short*)smem;                 // 128x64 swizzled
  short* Vs = (short*)(smem + 16384);       // 64x128 swizzled
  short* Ps = (short*)(smem + 32768);       // 64x128 swizzled

  const short* qb = qbf + ((size_t)bh * TTT + t0) * 64;
  const int trow_l = w * 16 + l15;
  bf16x8 qf0 = *(const bf16x8*)&qb[(size_t)trow_l * 64 + quad * 8];
  bf16x8 qf1 = *(const bf16x8*)&qb[(size_t)trow_l * 64 + 32 + quad * 8];

  f32x4 acc_o[4];
#pragma unroll
  for (int n = 0; n < 4; ++n) acc_o[n] = (f32x4){0.f, 0.f, 0.f, 0.f};
  float den[4] = {0.f, 0.f, 0.f, 0.f};

  const float* cm = cond_mask + (size_t)b * TSS;
  const short* kbase = kbf + (size_t)bh * TSS * 64;
  const short* vbase = vbf + (size_t)bh * KC * TSS;

  for (int s0 = 0; s0 < TSS; s0 += 128) {
    __syncthreads();
#pragma unroll
    for (int p = 0; p < 4; ++p) {
      int idx = tid + p * 256;
      int blk = idx & 7, sr = idx >> 3;
      *(uint4*)&Ks[sr * 64 + 8 * (blk ^ (sr & 7))] =
          *(const uint4*)&kbase[(size_t)(s0 + sr) * 64 + 8 * blk];
    }
#pragma unroll
    for (int p = 0; p < 4; ++p) {
      int idx = tid + p * 256;
      int blk = idx & 15, ch = idx >> 4;
      *(uint4*)&Vs[ch * 128 + 8 * (blk ^ (ch & 7))] =
          *(const uint4*)&vbase[(size_t)ch * TSS + s0 + 8 * blk];
    }
    __syncthreads();

#pragma unroll
    for (int n0 = 0; n0 < 8; ++n0) {
      int srow = n0 * 16 + l15;
      bf16x8 kf0 = *(const bf16x8*)&Ks[srow * 64 + 8 * (quad ^ (srow & 7))];
      bf16x8 kf1 = *(const bf16x8*)&Ks[srow * 64 + 8 * ((4 + quad) ^ (srow & 7))];
      f32x4 acc = (f32x4){0.f, 0.f, 0.f, 0.f};
      acc = __builtin_amdgcn_mfma_f32_16x16x32_bf16(qf0, kf0, acc, 0, 0, 0);
      acc = __builtin_amdgcn_mfma_f32_16x16x32_bf16(qf1, kf1, acc, 0, 0, 0);
      float mk = (cm[s0 + srow] != 0.f) ? 1.f : 0.f;
      int sblk = n0 * 2 + (l15 >> 3);
      int slow = l15 & 7;
#pragma unroll
      for (int r = 0; r < 4; ++r) {
        float e = __expf(acc[r] * 0.125f) * mk;
        den[r] += e;
        int trow = w * 16 + quad * 4 + r;
        Ps[trow * 128 + 8 * (sblk ^ (trow & 7)) + slow] = f2bf(e);
      }
    }

    {
      int trow = w * 16 + l15;
#pragma unroll
      for (int kt = 0; kt < 4; ++kt) {
        bf16x8 pf = *(const bf16x8*)&Ps[trow * 128 + 8 * ((kt * 4 + quad) ^ (trow & 7))];
#pragma unroll
        for (int n0 = 0; n0 < 4; ++n0) {
          int ch = n0 * 16 + l15;
          bf16x8 vf = *(const bf16x8*)&Vs[ch * 128 + 8 * ((kt * 4 + quad) ^ (ch & 7))];
          acc_o[n0] = __builtin_amdgcn_mfma_f32_16x16x32_bf16(pf, vf, acc_o[n0], 0, 0, 0);
        }
      }
    }
  }

  float rd[4];
#pragma unroll
  for (int r = 0; r < 4; ++r) {
    float d = den[r];
#pragma unroll
    for (int off = 1; off < 16; off <<= 1) d += __shfl_xor(d, off, 16);
    rd[r] = 1.f / fmaxf(d, 1e-30f);
  }

  __syncthreads();
  short* Os = (short*)smem;
#pragma unroll
  for (int n0 = 0; n0 < 4; ++n0)
#pragma unroll
    for (int r = 0; r < 4; ++r) {
      int ch = n0 * 16 + l15;
      int trow = w * 16 + quad * 4 + r;
      Os[trow * 64 + ch] = f2bf(acc_o[n0][r] * rd[r]);
    }
  __syncthreads();

  short* ob = obuf + ((size_t)b * TTT + t0) * CH + h * KC;
#pragma unroll
  for (int p = 0; p < 2; ++p) {
    int idx = tid + p * 256;
    int t = idx >> 3, c8 = idx & 7;
    *(uint4*)&ob[(size_t)t * CH + c8 * 8] = *(const uint4*)&Os[t * 64 + c8 * 8];
  }
}

// ---------------------------------------------------------------------------
// film_mfma (r9 exact, t-tile 64): the t32 variant regressed ~35 µs (r10).
// ---------------------------------------------------------------------------
__global__ __launch_bounds__(256) void film_mfma(
    const short* __restrict__ wfbf, const float* __restrict__ bf2,
    const short* __restrict__ ybf, const float* __restrict__ X,
    const float* __restrict__ xmask, float* __restrict__ out) {
  const int t0 = blockIdx.x * 64;
  const int b = blockIdx.y;
  const int tid = threadIdx.x;
  const int w = tid >> 6, lane = tid & 63;
  const int quad = lane >> 4, l15 = lane & 15;

  __shared__ __align__(16) short Ys[64 * 256];

  const short* yb = ybf + ((size_t)b * TTT + t0) * CH;
#pragma unroll
  for (int p = 0; p < 8; ++p) {
    int idx = tid + p * 256;
    int cb = idx & 31, tr = idx >> 5;
    *(uint4*)&Ys[tr * 256 + 8 * (cb ^ (tr & 7))] =
        *(const uint4*)&yb[(size_t)tr * CH + 8 * cb];
  }
  __syncthreads();

  const int mbase = w * 64;
  f32x4 accg[4][4], accb[4][4];
#pragma unroll
  for (int mf = 0; mf < 4; ++mf)
#pragma unroll
    for (int nt = 0; nt < 4; ++nt) {
      accg[mf][nt] = (f32x4){0.f, 0.f, 0.f, 0.f};
      accb[mf][nt] = (f32x4){0.f, 0.f, 0.f, 0.f};
    }

#pragma unroll
  for (int k0 = 0; k0 < 256; k0 += 32) {
    const int cb0 = (k0 >> 3) + quad;
    bf16x8 bfr[4];
#pragma unroll
    for (int nt = 0; nt < 4; ++nt) {
      int tr = nt * 16 + l15;
      bfr[nt] = *(const bf16x8*)&Ys[tr * 256 + 8 * (cb0 ^ (tr & 7))];
    }
#pragma unroll
    for (int mf = 0; mf < 4; ++mf) {
      int rowg = mbase + mf * 16 + l15;
      bf16x8 ag = *(const bf16x8*)&wfbf[(size_t)rowg * 256 + k0 + quad * 8];
      bf16x8 ab = *(const bf16x8*)&wfbf[(size_t)(256 + rowg) * 256 + k0 + quad * 8];
#pragma unroll
      for (int nt = 0; nt < 4; ++nt) {
        accg[mf][nt] = __builtin_amdgcn_mfma_f32_16x16x32_bf16(ag, bfr[nt], accg[mf][nt], 0, 0, 0);
        accb[mf][nt] = __builtin_amdgcn_mfma_f32_16x16x32_bf16(ab, bfr[nt], accb[mf][nt], 0, 0, 0);
      }
    }
  }

  const float* xb = X + (size_t)b * CH * TTT + t0;
  const float* xm = xmask + (size_t)b * TTT + t0;
  float* ob = out + (size_t)b * CH * TTT + t0;
  float xmv[4];
#pragma unroll
  for (int nt = 0; nt < 4; ++nt) xmv[nt] = xm[nt * 16 + l15];

#pragma unroll
  for (int mf = 0; mf < 4; ++mf) {
#pragma unroll
    for (int r = 0; r < 4; ++r) {
      int row = mbase + mf * 16 + quad * 4 + r;
      float bg = bf2[row];
      float bb = bf2[256 + row];
#pragma unroll
      for (int nt = 0; nt < 4; ++nt) {
        int t = nt * 16 + l15;
        float g  = accg[mf][nt][r] + bg;
        float bt = accb[mf][nt][r] + bb;
        float xv = xb[(size_t)row * TTT + t];
        ob[(size_t)row * TTT + t] = (xv * g + bt) * xmv[nt];
      }
    }
  }
}

// ---------------------------------------------------------------------------
extern "C" void kernel_launch(void* const* d_in, const int* in_sizes, int n_in,
                              void* d_out, int out_size, void* d_ws, size_t ws_size,
                              hipStream_t stream) {
  const float* x           = (const float*)d_in[0];
  const float* x_mask      = (const float*)d_in[1];
  const float* cond_latent = (const float*)d_in[2];
  const float* cond_mask   = (const float*)d_in[3];
  const float* w_cond      = (const float*)d_in[4];
  const float* b_cond      = (const float*)d_in[5];
  const float* wq          = (const float*)d_in[6];
  const float* bq          = (const float*)d_in[7];
  const float* wk          = (const float*)d_in[8];
  const float* bk          = (const float*)d_in[9];
  const float* wv          = (const float*)d_in[10];
  const float* bv          = (const float*)d_in[11];
  const float* wo          = (const float*)d_in[12];
  const float* bo          = (const float*)d_in[13];
  const float* w_film      = (const float*)d_in[14];
  const float* b_film      = (const float*)d_in[15];
  float* out = (float*)d_out;

  float* ws = (float*)d_ws;
  float* k_buf = ws;                    // (region reused by o_bf)
  float* v_buf = k_buf + 2097152;
  float* wk2   = v_buf + 2097152;       // (unused fp32 slots kept for layout)
  float* wv2   = wk2 + 131072;
  float* wf2   = wv2 + 131072;
  float* bk2   = wf2 + 131072;          // 256
  float* bv2   = bk2 + 256;             // 256
  float* bf2   = bv2 + 256;             // 512
  float* zbuf  = bf2 + 512;             // (unused now)
  short* k_bf  = (short*)(zbuf + 512);  // 16*4*512*64 bf16
  short* v_bf  = k_bf + 2097152;        // 16*4*64*512 bf16
  short* wf2bf = v_bf + 2097152;        // 512*256 bf16
  short* q_bf  = wf2bf + 131072;        // 16*4*2048*64 bf16
  short* wq_bf = q_bf + 8388608;        // 256*256 bf16
  short* wkv_bf = wq_bf + 65536;        // 512*512 bf16 (K rows || V rows)
  short* o_bf  = (short*)k_buf;         // 16*2048*256 bf16 (aliases k/v_buf)

  dim3 blk(256);

  // --- all weight folding in ONE launch (was memset + 4 kernels) ---
  prep<<<dim3(100), blk, 0, stream>>>(
      wk, wv, w_cond, wkv_bf, w_film, wo, wf2bf, wq, wq_bf,
      bk, bv, b_cond, b_film, bo, bk2, bv2, bf2);

  // --- main pipeline ---
  // Fused Q + K/V projections
  gemm_qkv_mfma<<<dim3(1024), blk, 0, stream>>>(
      wq_bf, bq, x, q_bf, wkv_bf, bk2, bv2, cond_latent, k_bf, v_bf);
  // MFMA attention (r0 structure, 64 t/block)
  attn_mfma<<<dim3(32, 4, 16), blk, 0, stream>>>(q_bf, k_bf, v_bf, cond_mask, o_bf);
  // MFMA film + final output (t-tile 64)
  film_mfma<<<dim3(32, 16), blk, 0, stream>>>(wf2bf, bf2, o_bf, x, x_mask, out);
}